// Round 6
// baseline (30.941 us; speedup 1.0000x reference)
//
#include <hip/hip_runtime.h>
#include <math.h>

#define NF   640
#define IMGN 256
#define NPIX (IMGN * IMGN)
#define TEXN 6
#define TPB  512            // 8 waves
#define PXW  64             // pixels per block (row segment)
#define NCH  8              // face chunks == waves
#define CHF  (NF / NCH)     // 80 faces per chunk

// ws float4 layout (2560 entries, 40 KB):
//   ws[2f+0] = A  {v0x, v0y, ex, ey}
//   ws[2f+1] = B  {dx, dy, dets, z0}
//   ws[1280+f] = C {z1, z2, light, 0}
//   ws[1920+f] = BB {xmin-pad, xmax+pad, ymin-pad, ymax+pad}
//
// CORRECTNESS CONTRACT (bit-exact vs numpy f32 ref, verified R2-R5):
//  - fp contract OFF, true IEEE '/', identical op order on decision path
//  - sign gate == post-division w>=0 test (IEEE sign rules)
//  - bbox cull conservative (pad (ext+1)*1e-6 >> ~ext*2^-23 accept slack);
//    degenerate faces get empty bbox == det_ok mask
//  - render copies records verbatim to LDS; shade recomputes w with
//    identical ops on identical bits

__global__ __launch_bounds__(256) void setup_kernel(
    const float* __restrict__ verts,   // 400*3 f32
    const int*   __restrict__ faces,   // 640*3 i32
    float4* __restrict__ ws)
{
#pragma clang fp contract(off)
    int f = (int)(blockIdx.x * 256 + threadIdx.x);
    if (f >= NF) return;
    const float EPSf = 1e-8f;

    int ia = faces[3 * f + 0];
    int ib = faces[3 * f + 1];
    int ic = faces[3 * f + 2];
    float ax = verts[3 * ia], ay = verts[3 * ia + 1], az = verts[3 * ia + 2];
    float bx = verts[3 * ib], by = verts[3 * ib + 1], bz = verts[3 * ib + 2];
    float cx = verts[3 * ic], cy = verts[3 * ic + 1], cz = verts[3 * ic + 2];

    // lighting (value-only path)
    float e1x = bx - ax, e1y = by - ay, e1z = bz - az;
    float e2x = cx - ax, e2y = cy - ay, e2z = cz - az;
    float nx = e1y * e2z - e1z * e2y;
    float ny = e1z * e2x - e1x * e2z;
    float nz = e1x * e2y - e1y * e2x;
    float nn = sqrtf((nx * nx + ny * ny) + nz * nz) + EPSf;
    float diff = nz / nn;
    diff = diff > 0.0f ? diff : 0.0f;
    float light = 0.5f + 0.5f * diff;

    // project: vc = [x, y, z+2], wfov == 1.0f exactly
    float z0 = az + 2.0f, z1 = bz + 2.0f, z2 = cz + 2.0f;
    float den0 = z0 * 1.0f + EPSf;
    float den1 = z1 * 1.0f + EPSf;
    float den2 = z2 * 1.0f + EPSf;
    float px0 = ax / den0, py0 = ay / den0;
    float px1 = bx / den1, py1 = by / den1;
    float px2 = cx / den2, py2 = cy / den2;

    float dx = px1 - px0, dy = py1 - py0;
    float ex = px2 - px0, ey = py2 - py0;
    float det = dx * ey - dy * ex;
    bool ok = fabsf(det) > 1e-8f;

    ws[2 * f + 0]  = make_float4(px0, py0, ex, ey);
    ws[2 * f + 1]  = make_float4(dx, dy, ok ? det : 1.0f, z0);
    ws[1280 + f]   = make_float4(z1, z2, light, 0.0f);

    if (ok) {
        float xmin = fminf(px0, fminf(px1, px2));
        float xmax = fmaxf(px0, fmaxf(px1, px2));
        float ymin = fminf(py0, fminf(py1, py2));
        float ymax = fmaxf(py0, fmaxf(py1, py2));
        float padx = (fmaxf(fabsf(xmin), fabsf(xmax)) + 1.0f) * 1e-6f;
        float pady = (fmaxf(fabsf(ymin), fabsf(ymax)) + 1.0f) * 1e-6f;
        ws[1920 + f] = make_float4(xmin - padx, xmax + padx,
                                   ymin - pady, ymax + pady);
    } else {
        ws[1920 + f] = make_float4(3e30f, -3e30f, 3e30f, -3e30f); // empty
    }
}

__global__ __launch_bounds__(TPB) void render_kernel(
    const float4* __restrict__ ws,
    const float* __restrict__ tex,    // 640*6*6*6*3 f32
    float* __restrict__ out)          // 3*65536 f32 (planar CHW)
{
#pragma clang fp contract(off)
    __shared__ float4 rec[1920];      // [2f]=A [2f+1]=B [1280+f]=C
    __shared__ unsigned short sList[NCH][CHF];
    __shared__ float rD[NCH][PXW];
    __shared__ int   rI[NCH][PXW];
    // LDS total = 30720 + 1280 + 2048 + 2048 = 36096 B -> 4 blocks/CU

    const int tid  = (int)threadIdx.x;
    const int wid  = tid >> 6;
    const int lane = tid & 63;
    const int p0   = (int)blockIdx.x * PXW;
    const int pi   = p0 >> 8;          // row (uniform per block)
    const int pj0  = p0 & (IMGN - 1);  // first col

    const float by    = -(((pi + 0.5f) / (float)IMGN) * 2.0f - 1.0f);
    const float bxmin = ((pj0 + 0.5f) / (float)IMGN) * 2.0f - 1.0f;
    const float bxmax = ((pj0 + (PXW - 1) + 0.5f) / (float)IMGN) * 2.0f - 1.0f;

    // ---- coalesced prefetch of all face records into LDS ----
    #pragma unroll
    for (int r = 0; r < 4; ++r) {
        int i = r * TPB + tid;
        if (i < 1920) rec[i] = ws[i];
    }

    // ---- cull from global bboxes (coalesced, read once, no reuse) ----
    const int fbeg = wid * CHF;
    int cnt = 0;
    for (int r = 0; r < 2; ++r) {
        int idx = r * 64 + lane;
        int f = fbeg + idx;
        bool pred = false;
        if (idx < CHF) {
            float4 bb = ws[1920 + f];
            pred = (bb.x <= bxmax) && (bb.y >= bxmin) &&
                   (bb.z <= by)    && (bb.w >= by);
        }
        unsigned long long m = __ballot(pred);
        if (pred)
            sList[wid][cnt + (int)__popcll(m & ((1ull << lane) - 1ull))] =
                (unsigned short)f;
        cnt += (int)__popcll(m);
    }
    __syncthreads();   // records + lists ready

    // ---- raster this wave's candidates (LDS broadcast reads) ----
    const float ppx = ((pj0 + lane + 0.5f) / (float)IMGN) * 2.0f - 1.0f;
    const float ppy = by;

    float best = 1e30f;
    int   bi = -1;

    for (int k = 0; k < cnt; ++k) {
        int f = (int)sList[wid][k];
        float4 a = rec[2 * f];        // v0x v0y ex ey
        float4 b = rec[2 * f + 1];    // dx dy det z0
        float qx = ppx - a.x;
        float qy = ppy - a.y;
        float n1 = qx * a.w - qy * a.z;
        float n2 = b.x * qy - b.y * qx;
        // sign gate == (w1>=0 && w2>=0) after IEEE division, bit-exact
        bool pass = (b.z > 0.0f) ? (n1 >= 0.0f && n2 >= 0.0f)
                                 : (n1 <= 0.0f && n2 <= 0.0f);
        if (pass) {
            float w1 = n1 / b.z;
            float w2 = n2 / b.z;
            float w0 = (1.0f - w1) - w2;
            if (w0 >= 0.0f) {
                float4 c = rec[1280 + f];   // z1 z2 light
                float depth = ((w0 * b.w) + (w1 * c.x)) + (w2 * c.y);
                if (depth > 0.0f && depth < best) {
                    best = depth; bi = f;
                }
            }
        }
    }

    rD[wid][lane] = best;
    rI[wid][lane] = bi;
    __syncthreads();

    // ---- wave 0: argmin-merge 8 chunks (ascending => first-occurrence),
    //      recompute w bit-identically, shade, write ----
    if (tid < PXW) {
        float bd = rD[0][tid];
        int   fi = rI[0][tid];
        for (int c = 1; c < NCH; ++c) {
            float d = rD[c][tid];
            if (d < bd) { bd = d; fi = rI[c][tid]; }
        }

        int pp = p0 + tid;
        float r = 0.0f, g = 0.0f, b = 0.0f;
        if (fi >= 0) {
            float4 a2 = rec[2 * fi];
            float4 b2 = rec[2 * fi + 1];
            float sx = ((pj0 + tid + 0.5f) / (float)IMGN) * 2.0f - 1.0f;
            float qx = sx - a2.x;
            float qy = by - a2.y;
            float n1 = qx * a2.w - qy * a2.z;
            float n2 = b2.x * qy - b2.y * qx;
            float w1 = n1 / b2.z;
            float w2 = n2 / b2.z;
            float w0 = (1.0f - w1) - w2;

            int i0 = (int)(w0 * (float)TEXN);
            int i1 = (int)(w1 * (float)TEXN);
            int i2 = (int)(w2 * (float)TEXN);
            i0 = i0 < 0 ? 0 : (i0 > TEXN - 1 ? TEXN - 1 : i0);
            i1 = i1 < 0 ? 0 : (i1 > TEXN - 1 ? TEXN - 1 : i1);
            i2 = i2 < 0 ? 0 : (i2 > TEXN - 1 ? TEXN - 1 : i2);
            const float* tp = tex + (size_t)((((fi * TEXN + i0) * TEXN + i1) * TEXN + i2) * 3);
            float light = rec[1280 + fi].z;
            r = tanhf(tp[0]) * light;
            g = tanhf(tp[1]) * light;
            b = tanhf(tp[2]) * light;
        }
        out[pp]            = r;
        out[NPIX + pp]     = g;
        out[2 * NPIX + pp] = b;
    }
}

extern "C" void kernel_launch(void* const* d_in, const int* in_sizes, int n_in,
                              void* d_out, int out_size, void* d_ws, size_t ws_size,
                              hipStream_t stream) {
    (void)in_sizes; (void)n_in; (void)ws_size; (void)out_size;
    const float* verts = (const float*)d_in[0];
    const int*   faces = (const int*)d_in[1];
    const float* tex   = (const float*)d_in[2];
    float*       out   = (float*)d_out;
    float4*      ws    = (float4*)d_ws;   // 2560 float4 = 40 KB

    setup_kernel<<<(NF + 255) / 256, 256, 0, stream>>>(verts, faces, ws);
    render_kernel<<<NPIX / PXW, TPB, 0, stream>>>(ws, tex, out);
}